// Round 9
// baseline (181.345 us; speedup 1.0000x reference)
//
#include <hip/hip_runtime.h>
#include <hip/hip_bf16.h>
#include <math.h>

#define N_PAIR 8192
#define DIM 128
#define L2REG 0.05f
#define LOG2E 1.44269504088896340736f
#define LN2 0.69314718055994530942f
#define SHIFT 64.0f

#define CS 64                           // column splits
#define BM 256                          // rows per block (4 waves x 64 rows)
#define COLS_PER_BLOCK (N_PAIR / CS)    // 128
#define NTILES (COLS_PER_BLOCK / 16)    // 8
#define NCHUNK (COLS_PER_BLOCK * DIM * 2 / 16)  // 2048 16B chunks (32 KB)

typedef __attribute__((ext_vector_type(8))) short short8;
typedef __attribute__((ext_vector_type(4))) float f32x4;

static __device__ __forceinline__ float fast_exp2(float x) {
#if __has_builtin(__builtin_amdgcn_exp2f)
  return __builtin_amdgcn_exp2f(x);
#else
  float r;
  asm("v_exp_f32 %0, %1" : "=v"(r) : "v"(x));
  return r;
#endif
}

static __device__ __forceinline__ void gload_lds16(const void* g, void* l) {
  __builtin_amdgcn_global_load_lds(
      (const __attribute__((address_space(1))) unsigned int*)g,
      (__attribute__((address_space(3))) unsigned int*)l, 16, 0, 0);
}

// ---------------- prep: deinterleave, scale anc by log2e, cast bf16, norms + diag ----
__global__ __launch_bounds__(256) void prep_kernel(
    const float* __restrict__ img,
    ushort* __restrict__ anc_bf, ushort* __restrict__ pos_bf,
    float* __restrict__ diag, float* __restrict__ na, float* __restrict__ npn) {
  int pair = blockIdx.x * 4 + (threadIdx.x >> 6);
  int lane = threadIdx.x & 63;
  const float4* base = (const float4*)(img + (size_t)pair * 2 * DIM);
  float4 v = base[lane];
  float4 o;
  o.x = __shfl_xor(v.x, 32);
  o.y = __shfl_xor(v.y, 32);
  o.z = __shfl_xor(v.z, 32);
  o.w = __shfl_xor(v.w, 32);

  float ss = v.x * v.x + v.y * v.y + v.z * v.z + v.w * v.w;
  float sd = v.x * o.x + v.y * o.y + v.z * o.z + v.w * o.w;
  #pragma unroll
  for (int off = 1; off < 32; off <<= 1) {
    ss += __shfl_xor(ss, off);
    sd += __shfl_xor(sd, off);
  }
  float ss_other = __shfl_xor(ss, 32);
  if (lane == 0) {
    diag[pair] = sd;
    na[pair] = sqrtf(ss);
    npn[pair] = sqrtf(ss_other);
  }

  bool isAnc = lane < 32;
  float sc = isAnc ? LOG2E : 1.0f;           // pre-scale anc: G arrives in log2 units
  __hip_bfloat16 b0 = __float2bfloat16(v.x * sc);
  __hip_bfloat16 b1 = __float2bfloat16(v.y * sc);
  __hip_bfloat16 b2 = __float2bfloat16(v.z * sc);
  __hip_bfloat16 b3 = __float2bfloat16(v.w * sc);
  ushort4 u;
  u.x = *(ushort*)&b0; u.y = *(ushort*)&b1;
  u.z = *(ushort*)&b2; u.w = *(ushort*)&b3;
  ushort* dst = isAnc ? (anc_bf + (size_t)pair * DIM + 4 * lane)
                      : (pos_bf + (size_t)pair * DIM + 4 * (lane - 32));
  *(ushort4*)dst = u;
}

// ---------------- main: R6 per-wave structure, half panel -> 2x occupancy ----------
// grid = 32 rb x 64 cs = 2048 blocks of 256 threads (4 waves x 64 rows).
// B panel 128 cols = 32 KB LDS -> 4 blocks/CU (16 waves/CU), VGPR cap 128.
// Same one-barrier, full-unroll, swizzled-panel body as R5/R6.
__global__ __launch_bounds__(256, 4) void lse_kernel(
    const ushort* __restrict__ anc_bf, const ushort* __restrict__ pos_bf,
    float* __restrict__ part_s) {
  __shared__ short8 ldsb[NCHUNK];   // 32 KB: 16B-chunk i at slot i^((i>>4)&7)

  int tid = threadIdx.x;
  int w = tid >> 6, lane = tid & 63;

  // XCD-grouped bijective remap of the 32x64 (rb, cs) grid
  int n = blockIdx.x;
  int xcd = n & 7, m = n >> 3;                 // m in [0,256)
  int rb = (xcd & 3) * 8 + (m & 7);            // 8 row-blocks per region
  int cs = (xcd >> 2) * 32 + (m >> 3);         // 32 col-splits per region

  int row0 = rb * BM + w * 64;
  int colbase = cs * COLS_PER_BLOCK;
  int lrow = lane & 15, g = lane >> 4;

  // stage B panel: 8 chunks per thread (linear LDS dest, inverse-swizzled src)
  const char* pbase = (const char*)(pos_bf + (size_t)colbase * DIM);
  #pragma unroll
  for (int t = 0; t < 8; ++t) {
    int i = t * 256 + tid;
    int src = (i ^ ((i >> 4) & 7)) << 4;
    gload_lds16(pbase + src, &ldsb[i]);
  }

  // A fragments: 64 rows x 128 K resident in registers (16 x short8 = 64 VGPR)
  short8 afrag[4][4];
  #pragma unroll
  for (int rt = 0; rt < 4; ++rt) {
    const ushort* ab = anc_bf + (size_t)(row0 + rt * 16 + lrow) * DIM + g * 8;
    #pragma unroll
    for (int ks = 0; ks < 4; ++ks)
      afrag[rt][ks] = *(const short8*)(ab + ks * 32);
  }

  float s[16];
  #pragma unroll
  for (int i = 0; i < 16; ++i) s[i] = 0.f;
  const f32x4 cinit = {-SHIFT, -SHIFT, -SHIFT, -SHIFT};

  __syncthreads();   // the only barrier

  #pragma unroll
  for (int T = 0; T < NTILES; ++T) {
    short8 b[4];
    int col = (T << 4) + lrow;
    #pragma unroll
    for (int ks = 0; ks < 4; ++ks) {
      int idx = ((col << 4) + (ks << 2) + g) ^ (col & 7);
      b[ks] = ldsb[idx];
    }
    #pragma unroll
    for (int rt = 0; rt < 4; ++rt) {
      f32x4 acc = __builtin_amdgcn_mfma_f32_16x16x32_bf16(afrag[rt][0], b[0], cinit, 0, 0, 0);
      acc = __builtin_amdgcn_mfma_f32_16x16x32_bf16(afrag[rt][1], b[1], acc, 0, 0, 0);
      acc = __builtin_amdgcn_mfma_f32_16x16x32_bf16(afrag[rt][2], b[2], acc, 0, 0, 0);
      acc = __builtin_amdgcn_mfma_f32_16x16x32_bf16(afrag[rt][3], b[3], acc, 0, 0, 0);
      s[rt * 4 + 0] += fast_exp2(acc[0]);
      s[rt * 4 + 1] += fast_exp2(acc[1]);
      s[rt * 4 + 2] += fast_exp2(acc[2]);
      s[rt * 4 + 3] += fast_exp2(acc[3]);
    }
  }

  // reduce s across the 16 lanes sharing each row
  #pragma unroll
  for (int i = 0; i < 16; ++i) {
    float ss = s[i];
    ss += __shfl_xor(ss, 1);
    ss += __shfl_xor(ss, 2);
    ss += __shfl_xor(ss, 4);
    ss += __shfl_xor(ss, 8);
    s[i] = ss;
  }
  if (lrow == 0) {
    #pragma unroll
    for (int rt = 0; rt < 4; ++rt)
      #pragma unroll
      for (int r = 0; r < 4; ++r)
        part_s[(size_t)cs * N_PAIR + (row0 + rt * 16 + g * 4 + r)] = s[rt * 4 + r];
  }
}

// ---------------- merge: combine column splits, add diag/norm terms ----------------
__global__ __launch_bounds__(256) void merge_kernel(
    const float* __restrict__ part_s,
    const float* __restrict__ diag, const float* __restrict__ na,
    const float* __restrict__ npn, float* __restrict__ blocksum) {
  int i = blockIdx.x * 256 + threadIdx.x;
  float S = 0.f;
  #pragma unroll
  for (int c = 0; c < CS; ++c)
    S += part_s[(size_t)c * N_PAIR + i];
  float lse = (SHIFT + log2f(S)) * LN2;
  float contrib = (lse - diag[i]) * (1.0f / N_PAIR)
                + L2REG * (na[i] * (1.0f / N_PAIR) + npn[i] * (1.0f / DIM));
  #pragma unroll
  for (int off = 32; off; off >>= 1) contrib += __shfl_xor(contrib, off);
  __shared__ float red[4];
  int lane = threadIdx.x & 63, wv = threadIdx.x >> 6;
  if (lane == 0) red[wv] = contrib;
  __syncthreads();
  if (threadIdx.x == 0)
    blocksum[blockIdx.x] = red[0] + red[1] + red[2] + red[3];
}

// ---------------- final: reduce 32 block sums ----------------
__global__ __launch_bounds__(64) void final_kernel(
    const float* __restrict__ blocksum, float* __restrict__ out, int nblocks) {
  float v = ((int)threadIdx.x < nblocks) ? blocksum[threadIdx.x] : 0.f;
  #pragma unroll
  for (int off = 32; off; off >>= 1) v += __shfl_xor(v, off);
  if (threadIdx.x == 0) out[0] = v;
}

extern "C" void kernel_launch(void* const* d_in, const int* in_sizes, int n_in,
                              void* d_out, int out_size, void* d_ws, size_t ws_size,
                              hipStream_t stream) {
  const float* img = (const float*)d_in[0];
  float* out = (float*)d_out;

  char* w = (char*)d_ws;
  ushort* anc_bf = (ushort*)w;                                  // 2 MB
  ushort* pos_bf = (ushort*)(w + (size_t)2 * 1024 * 1024);      // 2 MB
  float* diag = (float*)(w + (size_t)4 * 1024 * 1024);          // 32 KB
  float* na = diag + N_PAIR;                                    // 32 KB
  float* npn = na + N_PAIR;                                     // 32 KB
  float* part_s = npn + N_PAIR;                                 // 2 MB  [cs][row]
  float* blocksum = part_s + (size_t)N_PAIR * CS;               // 128 B

  prep_kernel<<<N_PAIR / 4, 256, 0, stream>>>(img, anc_bf, pos_bf, diag, na, npn);
  lse_kernel<<<(N_PAIR / BM) * CS, 256, 0, stream>>>(anc_bf, pos_bf, part_s);
  merge_kernel<<<N_PAIR / 256, 256, 0, stream>>>(part_s, diag, na, npn, blocksum);
  final_kernel<<<1, 64, 0, stream>>>(blocksum, out, N_PAIR / 256);
}

// Round 10
// 56.552 us; speedup vs baseline: 3.2067x; 3.2067x over previous
//
#include <hip/hip_runtime.h>
#include <hip/hip_bf16.h>
#include <math.h>

#define N_PAIR 8192
#define DIM 128
#define L2REG 0.05f
#define LOG2E 1.44269504088896340736f
#define LN2 0.69314718055994530942f
#define SHIFT 64.0f

#define CS 64                           // column splits
#define BM 256                          // rows per block (4 waves x 64 rows)
#define COLS_PER_BLOCK (N_PAIR / CS)    // 128
#define NTILES (COLS_PER_BLOCK / 16)    // 8
#define NCHUNK (COLS_PER_BLOCK * DIM * 2 / 16)  // 2048 16B chunks (32 KB)

typedef __attribute__((ext_vector_type(8))) short short8;
typedef __attribute__((ext_vector_type(4))) float f32x4;

static __device__ __forceinline__ float fast_exp2(float x) {
#if __has_builtin(__builtin_amdgcn_exp2f)
  return __builtin_amdgcn_exp2f(x);
#else
  float r;
  asm("v_exp_f32 %0, %1" : "=v"(r) : "v"(x));
  return r;
#endif
}

static __device__ __forceinline__ void gload_lds16(const void* g, void* l) {
  __builtin_amdgcn_global_load_lds(
      (const __attribute__((address_space(1))) unsigned int*)g,
      (__attribute__((address_space(3))) unsigned int*)l, 16, 0, 0);
}

// ---------------- prep: deinterleave, scale anc by log2e, cast bf16, norms + diag ----
__global__ __launch_bounds__(256) void prep_kernel(
    const float* __restrict__ img,
    ushort* __restrict__ anc_bf, ushort* __restrict__ pos_bf,
    float* __restrict__ diag, float* __restrict__ na, float* __restrict__ npn) {
  int pair = blockIdx.x * 4 + (threadIdx.x >> 6);
  int lane = threadIdx.x & 63;
  const float4* base = (const float4*)(img + (size_t)pair * 2 * DIM);
  float4 v = base[lane];
  float4 o;
  o.x = __shfl_xor(v.x, 32);
  o.y = __shfl_xor(v.y, 32);
  o.z = __shfl_xor(v.z, 32);
  o.w = __shfl_xor(v.w, 32);

  float ss = v.x * v.x + v.y * v.y + v.z * v.z + v.w * v.w;
  float sd = v.x * o.x + v.y * o.y + v.z * o.z + v.w * o.w;
  #pragma unroll
  for (int off = 1; off < 32; off <<= 1) {
    ss += __shfl_xor(ss, off);
    sd += __shfl_xor(sd, off);
  }
  float ss_other = __shfl_xor(ss, 32);
  if (lane == 0) {
    diag[pair] = sd;
    na[pair] = sqrtf(ss);
    npn[pair] = sqrtf(ss_other);
  }

  bool isAnc = lane < 32;
  float sc = isAnc ? LOG2E : 1.0f;           // pre-scale anc: G arrives in log2 units
  __hip_bfloat16 b0 = __float2bfloat16(v.x * sc);
  __hip_bfloat16 b1 = __float2bfloat16(v.y * sc);
  __hip_bfloat16 b2 = __float2bfloat16(v.z * sc);
  __hip_bfloat16 b3 = __float2bfloat16(v.w * sc);
  ushort4 u;
  u.x = *(ushort*)&b0; u.y = *(ushort*)&b1;
  u.z = *(ushort*)&b2; u.w = *(ushort*)&b3;
  ushort* dst = isAnc ? (anc_bf + (size_t)pair * DIM + 4 * lane)
                      : (pos_bf + (size_t)pair * DIM + 4 * (lane - 32));
  *(ushort4*)dst = u;
}

// ---------------- main: R9 structure, launch_bounds(256,2) -> 128-VGPR step --------
// grid = 32 rb x 64 cs = 2048 blocks of 256 threads (4 waves x 64 rows).
// B panel 128 cols = 32 KB LDS. Compiler lands on the 128-VGPR occupancy step
// (observed R7) -> 16 waves/CU, no spill. One barrier, full unroll, swizzled panel.
__global__ __launch_bounds__(256, 2) void lse_kernel(
    const ushort* __restrict__ anc_bf, const ushort* __restrict__ pos_bf,
    float* __restrict__ part_s) {
  __shared__ short8 ldsb[NCHUNK];   // 32 KB: 16B-chunk i at slot i^((i>>4)&7)

  int tid = threadIdx.x;
  int w = tid >> 6, lane = tid & 63;

  // XCD-grouped bijective remap of the 32x64 (rb, cs) grid
  int n = blockIdx.x;
  int xcd = n & 7, m = n >> 3;                 // m in [0,256)
  int rb = (xcd & 3) * 8 + (m & 7);            // 8 row-blocks per region
  int cs = (xcd >> 2) * 32 + (m >> 3);         // 32 col-splits per region

  int row0 = rb * BM + w * 64;
  int colbase = cs * COLS_PER_BLOCK;
  int lrow = lane & 15, g = lane >> 4;

  // stage B panel: 8 chunks per thread (linear LDS dest, inverse-swizzled src)
  const char* pbase = (const char*)(pos_bf + (size_t)colbase * DIM);
  #pragma unroll
  for (int t = 0; t < 8; ++t) {
    int i = t * 256 + tid;
    int src = (i ^ ((i >> 4) & 7)) << 4;
    gload_lds16(pbase + src, &ldsb[i]);
  }

  // A fragments: 64 rows x 128 K resident in registers (16 x short8 = 64 VGPR)
  short8 afrag[4][4];
  #pragma unroll
  for (int rt = 0; rt < 4; ++rt) {
    const ushort* ab = anc_bf + (size_t)(row0 + rt * 16 + lrow) * DIM + g * 8;
    #pragma unroll
    for (int ks = 0; ks < 4; ++ks)
      afrag[rt][ks] = *(const short8*)(ab + ks * 32);
  }

  float s[16];
  #pragma unroll
  for (int i = 0; i < 16; ++i) s[i] = 0.f;
  const f32x4 cinit = {-SHIFT, -SHIFT, -SHIFT, -SHIFT};

  __syncthreads();   // the only barrier

  #pragma unroll
  for (int T = 0; T < NTILES; ++T) {
    short8 b[4];
    int col = (T << 4) + lrow;
    #pragma unroll
    for (int ks = 0; ks < 4; ++ks) {
      int idx = ((col << 4) + (ks << 2) + g) ^ (col & 7);
      b[ks] = ldsb[idx];
    }
    #pragma unroll
    for (int rt = 0; rt < 4; ++rt) {
      f32x4 acc = __builtin_amdgcn_mfma_f32_16x16x32_bf16(afrag[rt][0], b[0], cinit, 0, 0, 0);
      acc = __builtin_amdgcn_mfma_f32_16x16x32_bf16(afrag[rt][1], b[1], acc, 0, 0, 0);
      acc = __builtin_amdgcn_mfma_f32_16x16x32_bf16(afrag[rt][2], b[2], acc, 0, 0, 0);
      acc = __builtin_amdgcn_mfma_f32_16x16x32_bf16(afrag[rt][3], b[3], acc, 0, 0, 0);
      s[rt * 4 + 0] += fast_exp2(acc[0]);
      s[rt * 4 + 1] += fast_exp2(acc[1]);
      s[rt * 4 + 2] += fast_exp2(acc[2]);
      s[rt * 4 + 3] += fast_exp2(acc[3]);
    }
  }

  // reduce s across the 16 lanes sharing each row
  #pragma unroll
  for (int i = 0; i < 16; ++i) {
    float ss = s[i];
    ss += __shfl_xor(ss, 1);
    ss += __shfl_xor(ss, 2);
    ss += __shfl_xor(ss, 4);
    ss += __shfl_xor(ss, 8);
    s[i] = ss;
  }
  if (lrow == 0) {
    #pragma unroll
    for (int rt = 0; rt < 4; ++rt)
      #pragma unroll
      for (int r = 0; r < 4; ++r)
        part_s[(size_t)cs * N_PAIR + (row0 + rt * 16 + g * 4 + r)] = s[rt * 4 + r];
  }
}

// ---------------- merge: combine column splits, add diag/norm terms ----------------
__global__ __launch_bounds__(256) void merge_kernel(
    const float* __restrict__ part_s,
    const float* __restrict__ diag, const float* __restrict__ na,
    const float* __restrict__ npn, float* __restrict__ blocksum) {
  int i = blockIdx.x * 256 + threadIdx.x;
  float S = 0.f;
  #pragma unroll
  for (int c = 0; c < CS; ++c)
    S += part_s[(size_t)c * N_PAIR + i];
  float lse = (SHIFT + log2f(S)) * LN2;
  float contrib = (lse - diag[i]) * (1.0f / N_PAIR)
                + L2REG * (na[i] * (1.0f / N_PAIR) + npn[i] * (1.0f / DIM));
  #pragma unroll
  for (int off = 32; off; off >>= 1) contrib += __shfl_xor(contrib, off);
  __shared__ float red[4];
  int lane = threadIdx.x & 63, wv = threadIdx.x >> 6;
  if (lane == 0) red[wv] = contrib;
  __syncthreads();
  if (threadIdx.x == 0)
    blocksum[blockIdx.x] = red[0] + red[1] + red[2] + red[3];
}

// ---------------- final: reduce 32 block sums ----------------
__global__ __launch_bounds__(64) void final_kernel(
    const float* __restrict__ blocksum, float* __restrict__ out, int nblocks) {
  float v = ((int)threadIdx.x < nblocks) ? blocksum[threadIdx.x] : 0.f;
  #pragma unroll
  for (int off = 32; off; off >>= 1) v += __shfl_xor(v, off);
  if (threadIdx.x == 0) out[0] = v;
}

extern "C" void kernel_launch(void* const* d_in, const int* in_sizes, int n_in,
                              void* d_out, int out_size, void* d_ws, size_t ws_size,
                              hipStream_t stream) {
  const float* img = (const float*)d_in[0];
  float* out = (float*)d_out;

  char* w = (char*)d_ws;
  ushort* anc_bf = (ushort*)w;                                  // 2 MB
  ushort* pos_bf = (ushort*)(w + (size_t)2 * 1024 * 1024);      // 2 MB
  float* diag = (float*)(w + (size_t)4 * 1024 * 1024);          // 32 KB
  float* na = diag + N_PAIR;                                    // 32 KB
  float* npn = na + N_PAIR;                                     // 32 KB
  float* part_s = npn + N_PAIR;                                 // 2 MB  [cs][row]
  float* blocksum = part_s + (size_t)N_PAIR * CS;               // 128 B

  prep_kernel<<<N_PAIR / 4, 256, 0, stream>>>(img, anc_bf, pos_bf, diag, na, npn);
  lse_kernel<<<(N_PAIR / BM) * CS, 256, 0, stream>>>(anc_bf, pos_bf, part_s);
  merge_kernel<<<N_PAIR / 256, 256, 0, stream>>>(part_s, diag, na, npn, blocksum);
  final_kernel<<<1, 64, 0, stream>>>(blocksum, out, N_PAIR / 256);
}

// Round 11
// 37.771 us; speedup vs baseline: 4.8011x; 1.4972x over previous
//
#include <hip/hip_runtime.h>
#include <hip/hip_bf16.h>
#include <math.h>

#define N_PAIR 8192
#define DIM 128
#define L2REG 0.05f
#define LOG2E 1.44269504088896340736f
#define LN2 0.69314718055994530942f
#define SHIFT 64.0f

#define CS 16                           // column splits
#define RS 16                           // row splits
#define ROWS_PER_BLOCK (N_PAIR / RS)    // 512 (8 waves x 64 rows)
#define COLS_PER_BLOCK (N_PAIR / CS)    // 512
#define NTILES (COLS_PER_BLOCK / 16)    // 32
#define NCHUNK (COLS_PER_BLOCK * DIM * 2 / 16)  // 8192 16B chunks = 128 KB

typedef __attribute__((ext_vector_type(8))) short short8;
typedef __attribute__((ext_vector_type(4))) float f32x4;

static __device__ __forceinline__ float fast_exp2(float x) {
#if __has_builtin(__builtin_amdgcn_exp2f)
  return __builtin_amdgcn_exp2f(x);
#else
  float r;
  asm("v_exp_f32 %0, %1" : "=v"(r) : "v"(x));
  return r;
#endif
}

static __device__ __forceinline__ void gload_lds16(const void* g, void* l) {
  __builtin_amdgcn_global_load_lds(
      (const __attribute__((address_space(1))) unsigned int*)g,
      (__attribute__((address_space(3))) unsigned int*)l, 16, 0, 0);
}

// ---------------- prep: deinterleave, scale anc by log2e, cast bf16, norms + diag ----
__global__ __launch_bounds__(256) void prep_kernel(
    const float* __restrict__ img,
    ushort* __restrict__ anc_bf, ushort* __restrict__ pos_bf,
    float* __restrict__ diag, float* __restrict__ na, float* __restrict__ npn) {
  int pair = blockIdx.x * 4 + (threadIdx.x >> 6);
  int lane = threadIdx.x & 63;
  const float4* base = (const float4*)(img + (size_t)pair * 2 * DIM);
  float4 v = base[lane];
  float4 o;
  o.x = __shfl_xor(v.x, 32);
  o.y = __shfl_xor(v.y, 32);
  o.z = __shfl_xor(v.z, 32);
  o.w = __shfl_xor(v.w, 32);

  float ss = v.x * v.x + v.y * v.y + v.z * v.z + v.w * v.w;
  float sd = v.x * o.x + v.y * o.y + v.z * o.z + v.w * o.w;
  #pragma unroll
  for (int off = 1; off < 32; off <<= 1) {
    ss += __shfl_xor(ss, off);
    sd += __shfl_xor(sd, off);
  }
  float ss_other = __shfl_xor(ss, 32);
  if (lane == 0) {
    diag[pair] = sd;
    na[pair] = sqrtf(ss);
    npn[pair] = sqrtf(ss_other);
  }

  bool isAnc = lane < 32;
  float sc = isAnc ? LOG2E : 1.0f;           // pre-scale anc: G arrives in log2 units
  __hip_bfloat16 b0 = __float2bfloat16(v.x * sc);
  __hip_bfloat16 b1 = __float2bfloat16(v.y * sc);
  __hip_bfloat16 b2 = __float2bfloat16(v.z * sc);
  __hip_bfloat16 b3 = __float2bfloat16(v.w * sc);
  ushort4 u;
  u.x = *(ushort*)&b0; u.y = *(ushort*)&b1;
  u.z = *(ushort*)&b2; u.w = *(ushort*)&b3;
  ushort* dst = isAnc ? (anc_bf + (size_t)pair * DIM + 4 * lane)
                      : (pos_bf + (size_t)pair * DIM + 4 * (lane - 32));
  *(ushort4*)dst = u;
}

// ---------------- main: 512x512 tile, 1 block/CU, minimal panel traffic ------------
// grid = 16 rb x 16 cs = 256 blocks (1/CU) of 512 threads (8 waves x 64 rows).
// B panel 512 cols = 128 KB LDS staged once via global_load_lds (linear dest,
// inverse-swizzled src), one barrier, 32 fully-unrolled col-tiles.
// Total panel traffic (A+B) = 64 MB, half of R6's 128 MB.
__global__ __launch_bounds__(512, 2) void lse_kernel(
    const ushort* __restrict__ anc_bf, const ushort* __restrict__ pos_bf,
    float* __restrict__ part_s) {
  __shared__ short8 ldsb[NCHUNK];   // 128 KB: 16B-chunk i at slot i^((i>>4)&7)

  int tid = threadIdx.x;
  int w = tid >> 6, lane = tid & 63;
  int rb = blockIdx.x >> 4, cs = blockIdx.x & 15;
  int row0 = rb * ROWS_PER_BLOCK + w * 64;
  int colbase = cs * COLS_PER_BLOCK;
  int lrow = lane & 15, g = lane >> 4;

  // stage B panel: 16 chunks per thread (linear LDS dest, inverse-swizzled src)
  const char* pbase = (const char*)(pos_bf + (size_t)colbase * DIM);
  #pragma unroll
  for (int t = 0; t < 16; ++t) {
    int i = t * 512 + tid;
    int src = (i ^ ((i >> 4) & 7)) << 4;
    gload_lds16(pbase + src, &ldsb[i]);
  }

  // A fragments: 64 rows x 128 K resident in registers (16 x short8 = 64 VGPR)
  short8 afrag[4][4];
  #pragma unroll
  for (int rt = 0; rt < 4; ++rt) {
    const ushort* ab = anc_bf + (size_t)(row0 + rt * 16 + lrow) * DIM + g * 8;
    #pragma unroll
    for (int ks = 0; ks < 4; ++ks)
      afrag[rt][ks] = *(const short8*)(ab + ks * 32);
  }

  float s[16];
  #pragma unroll
  for (int i = 0; i < 16; ++i) s[i] = 0.f;
  const f32x4 cinit = {-SHIFT, -SHIFT, -SHIFT, -SHIFT};

  __syncthreads();   // the only barrier

  #pragma unroll
  for (int T = 0; T < NTILES; ++T) {
    short8 b[4];
    int col = (T << 4) + lrow;
    #pragma unroll
    for (int ks = 0; ks < 4; ++ks) {
      int idx = ((col << 4) + (ks << 2) + g) ^ (col & 7);
      b[ks] = ldsb[idx];
    }
    #pragma unroll
    for (int rt = 0; rt < 4; ++rt) {
      f32x4 acc = __builtin_amdgcn_mfma_f32_16x16x32_bf16(afrag[rt][0], b[0], cinit, 0, 0, 0);
      acc = __builtin_amdgcn_mfma_f32_16x16x32_bf16(afrag[rt][1], b[1], acc, 0, 0, 0);
      acc = __builtin_amdgcn_mfma_f32_16x16x32_bf16(afrag[rt][2], b[2], acc, 0, 0, 0);
      acc = __builtin_amdgcn_mfma_f32_16x16x32_bf16(afrag[rt][3], b[3], acc, 0, 0, 0);
      s[rt * 4 + 0] += fast_exp2(acc[0]);
      s[rt * 4 + 1] += fast_exp2(acc[1]);
      s[rt * 4 + 2] += fast_exp2(acc[2]);
      s[rt * 4 + 3] += fast_exp2(acc[3]);
    }
  }

  // reduce s across the 16 lanes sharing each row
  #pragma unroll
  for (int i = 0; i < 16; ++i) {
    float ss = s[i];
    ss += __shfl_xor(ss, 1);
    ss += __shfl_xor(ss, 2);
    ss += __shfl_xor(ss, 4);
    ss += __shfl_xor(ss, 8);
    s[i] = ss;
  }
  if (lrow == 0) {
    #pragma unroll
    for (int rt = 0; rt < 4; ++rt)
      #pragma unroll
      for (int r = 0; r < 4; ++r)
        part_s[(size_t)cs * N_PAIR + (row0 + rt * 16 + g * 4 + r)] = s[rt * 4 + r];
  }
}

// ---------------- merge: combine column splits, add diag/norm terms ----------------
__global__ __launch_bounds__(256) void merge_kernel(
    const float* __restrict__ part_s,
    const float* __restrict__ diag, const float* __restrict__ na,
    const float* __restrict__ npn, float* __restrict__ blocksum) {
  int i = blockIdx.x * 256 + threadIdx.x;
  float S = 0.f;
  #pragma unroll
  for (int c = 0; c < CS; ++c)
    S += part_s[(size_t)c * N_PAIR + i];
  float lse = (SHIFT + log2f(S)) * LN2;
  float contrib = (lse - diag[i]) * (1.0f / N_PAIR)
                + L2REG * (na[i] * (1.0f / N_PAIR) + npn[i] * (1.0f / DIM));
  #pragma unroll
  for (int off = 32; off; off >>= 1) contrib += __shfl_xor(contrib, off);
  __shared__ float red[4];
  int lane = threadIdx.x & 63, wv = threadIdx.x >> 6;
  if (lane == 0) red[wv] = contrib;
  __syncthreads();
  if (threadIdx.x == 0)
    blocksum[blockIdx.x] = red[0] + red[1] + red[2] + red[3];
}

// ---------------- final: reduce 32 block sums ----------------
__global__ __launch_bounds__(64) void final_kernel(
    const float* __restrict__ blocksum, float* __restrict__ out, int nblocks) {
  float v = ((int)threadIdx.x < nblocks) ? blocksum[threadIdx.x] : 0.f;
  #pragma unroll
  for (int off = 32; off; off >>= 1) v += __shfl_xor(v, off);
  if (threadIdx.x == 0) out[0] = v;
}

extern "C" void kernel_launch(void* const* d_in, const int* in_sizes, int n_in,
                              void* d_out, int out_size, void* d_ws, size_t ws_size,
                              hipStream_t stream) {
  const float* img = (const float*)d_in[0];
  float* out = (float*)d_out;

  char* w = (char*)d_ws;
  ushort* anc_bf = (ushort*)w;                                  // 2 MB
  ushort* pos_bf = (ushort*)(w + (size_t)2 * 1024 * 1024);      // 2 MB
  float* diag = (float*)(w + (size_t)4 * 1024 * 1024);          // 32 KB
  float* na = diag + N_PAIR;                                    // 32 KB
  float* npn = na + N_PAIR;                                     // 32 KB
  float* part_s = npn + N_PAIR;                                 // 512 KB [cs][row]
  float* blocksum = part_s + (size_t)N_PAIR * CS;               // 128 B

  prep_kernel<<<N_PAIR / 4, 256, 0, stream>>>(img, anc_bf, pos_bf, diag, na, npn);
  lse_kernel<<<RS * CS, 512, 0, stream>>>(anc_bf, pos_bf, part_s);
  merge_kernel<<<N_PAIR / 256, 256, 0, stream>>>(part_s, diag, na, npn, blocksum);
  final_kernel<<<1, 64, 0, stream>>>(blocksum, out, N_PAIR / 256);
}